// Round 5
// baseline (3974.169 us; speedup 1.0000x reference)
//
#include <hip/hip_runtime.h>
#include <math.h>

#define N_ROWS 32768
#define KCODES 8192
#define DIM 256
#define NZ (N_ROWS * DIM)
#define CAP 64
#define W_PRUNE 2e-4f

typedef __attribute__((ext_vector_type(8))) short short8v;
typedef __attribute__((ext_vector_type(4))) float float4v;

__device__ __forceinline__ float sqf(float x) { return __fmul_rn(x, x); }

__device__ __forceinline__ unsigned short f2bf(float f) {
  unsigned u = __float_as_uint(f);
  return (unsigned short)((u + 0x7fffu + ((u >> 16) & 1u)) >> 16);
}

// ---- codebook f32 -> bf16 convert ----
__global__ void vq_conv(const float* __restrict__ cb, short* __restrict__ chi) {
  int i = blockIdx.x * blockDim.x + threadIdx.x;
  const float* p = cb + (size_t)i * 8;
  float4v f0 = *(const float4v*)p;
  float4v f1 = *(const float4v*)(p + 4);
  short8v v;
  v[0] = (short)f2bf(f0[0]); v[1] = (short)f2bf(f0[1]);
  v[2] = (short)f2bf(f0[2]); v[3] = (short)f2bf(f0[3]);
  v[4] = (short)f2bf(f1[0]); v[5] = (short)f2bf(f1[1]);
  v[6] = (short)f2bf(f1[2]); v[7] = (short)f2bf(f1[3]);
  *(short8v*)(chi + (size_t)i * 8) = v;
}

// ---- exact ||c||^2, numpy-pairwise bitwise (16 lanes/code; verified pattern) ----
__global__ void vq_cc2(const float* __restrict__ cb, float* __restrict__ cc) {
  __shared__ __align__(16) float cs[16][260];
  const int tid = threadIdx.x;
  const int l = tid & 63;
  const int lr = (tid >> 6) * 4 + (l >> 4);      // local code 0..15
  const size_t C0 = (size_t)blockIdx.x * 16;

#pragma unroll
  for (int it = 0; it < 4; ++it) {
    int flat = it * 1024 + tid * 4;
    int r = flat >> 8, c = flat & 255;
    *(float4v*)&cs[r][c] = *(const float4v*)(cb + C0 * DIM + flat);
  }
  __syncthreads();

  const int b = (l >> 3) & 1, j = l & 7;
  const float* cr = cs[lr];
  float r = sqf(cr[b * 128 + j]);
  for (int i = 8; i < 128; i += 8) r = __fadd_rn(r, sqf(cr[b * 128 + i + j]));
  float rr[16];
  const int gbase = l & 48;
#pragma unroll
  for (int j2 = 0; j2 < 16; ++j2) rr[j2] = __shfl(r, gbase + j2, 64);
  float b0 = __fadd_rn(__fadd_rn(__fadd_rn(rr[0], rr[1]), __fadd_rn(rr[2], rr[3])),
                       __fadd_rn(__fadd_rn(rr[4], rr[5]), __fadd_rn(rr[6], rr[7])));
  float b1 = __fadd_rn(__fadd_rn(__fadd_rn(rr[8], rr[9]), __fadd_rn(rr[10], rr[11])),
                       __fadd_rn(__fadd_rn(rr[12], rr[13]), __fadd_rn(rr[14], rr[15])));
  if ((l & 15) == 0) cc[C0 + lr] = __fadd_rn(b0, b1);
}

// ---- screen v2: 2-pass threshold-emit, register-streamed B, no main-loop LDS ----
// 512 blocks x 256 thr. Wave w owns code-quarter w (16 codes of each 64-code
// tile) x ALL 64 rows of the block (4 h-frags in registers).
__launch_bounds__(256, 2)
__global__ void vq_screen2(const float* __restrict__ z, const short* __restrict__ chi,
                           int* __restrict__ cnt, unsigned short* __restrict__ cand) {
  __shared__ __align__(16) float smax[64][4];
  const int tid = threadIdx.x;
  const int w = tid >> 6, l = tid & 63;
  const int lc = l & 15;   // frag row/col lane
  const int lq = l >> 4;   // k-quadrant
  const int R0 = blockIdx.x * 64;

  // A-frags: row = R0 + h*16 + lc, k = s*32 + lq*8 .. +8  (validated pattern)
  short8v a[4][8];
#pragma unroll
  for (int h = 0; h < 4; ++h) {
    const float* zr = z + (size_t)(R0 + h * 16 + lc) * DIM + lq * 8;
#pragma unroll
    for (int s = 0; s < 8; ++s) {
      const float* p = zr + s * 32;
      float4v f0 = *(const float4v*)p;
      float4v f1 = *(const float4v*)(p + 4);
      short8v v;
      v[0] = (short)f2bf(f0[0]); v[1] = (short)f2bf(f0[1]);
      v[2] = (short)f2bf(f0[2]); v[3] = (short)f2bf(f0[3]);
      v[4] = (short)f2bf(f1[0]); v[5] = (short)f2bf(f1[1]);
      v[6] = (short)f2bf(f1[2]); v[7] = (short)f2bf(f1[3]);
      a[h][s] = v;
    }
  }

  short8v b0[8], b1[8];
  auto loadB = [&](int t, short8v (&br)[8]) {
    const short* cbase = chi + (size_t)(t * 64 + w * 16 + lc) * DIM + lq * 8;
#pragma unroll
    for (int s = 0; s < 8; ++s) br[s] = *(const short8v*)(cbase + s * 32);
  };
  auto mstep = [&](const short8v (&br)[8], float4v (&acc)[4]) {
#pragma unroll
    for (int s = 0; s < 8; ++s)
#pragma unroll
      for (int h = 0; h < 4; ++h)
        acc[h] = __builtin_amdgcn_mfma_f32_16x16x32_bf16(a[h][s], br[s], acc[h], 0, 0, 0);
  };

  // ---- pass 0: sample tiles 0,4,...,124 -> per-row sample max ----
  float rmx[4][4];
#pragma unroll
  for (int h = 0; h < 4; ++h)
#pragma unroll
    for (int r = 0; r < 4; ++r) rmx[h][r] = -INFINITY;

  auto p0step = [&](const short8v (&br)[8]) {
    float4v acc[4] = {{0.f,0.f,0.f,0.f},{0.f,0.f,0.f,0.f},{0.f,0.f,0.f,0.f},{0.f,0.f,0.f,0.f}};
    mstep(br, acc);
#pragma unroll
    for (int h = 0; h < 4; ++h)
#pragma unroll
      for (int r = 0; r < 4; ++r) rmx[h][r] = fmaxf(rmx[h][r], acc[h][r]);
  };

  loadB(0, b0);
  for (int i = 0; i < 32; i += 2) {
    loadB(i * 4 + 4, b1);
    p0step(b0);
    if (i + 2 < 32) loadB(i * 4 + 8, b0);
    p0step(b1);
  }

  // cross-lane + cross-wave row max -> thresholds
#pragma unroll
  for (int h = 0; h < 4; ++h)
#pragma unroll
    for (int r = 0; r < 4; ++r) {
      float m = rmx[h][r];
      m = fmaxf(m, __shfl_xor(m, 1, 16));
      m = fmaxf(m, __shfl_xor(m, 2, 16));
      m = fmaxf(m, __shfl_xor(m, 4, 16));
      m = fmaxf(m, __shfl_xor(m, 8, 16));
      if (lc == 0) smax[h * 16 + lq * 4 + r][w] = m;
    }
  __syncthreads();
  float thr[4][4];
#pragma unroll
  for (int h = 0; h < 4; ++h)
#pragma unroll
    for (int r = 0; r < 4; ++r) {
      float4v mm = *(const float4v*)smax[h * 16 + lq * 4 + r];
      thr[h][r] = fmaxf(fmaxf(mm[0], mm[1]), fmaxf(mm[2], mm[3])) - W_PRUNE;
    }

  // ---- pass 1: full sweep, emit scores >= thr ----
  auto p1step = [&](const short8v (&br)[8], int t) {
    float4v acc[4] = {{0.f,0.f,0.f,0.f},{0.f,0.f,0.f,0.f},{0.f,0.f,0.f,0.f},{0.f,0.f,0.f,0.f}};
    mstep(br, acc);
    const int code = t * 64 + w * 16 + lc;
#pragma unroll
    for (int h = 0; h < 4; ++h)
#pragma unroll
      for (int r = 0; r < 4; ++r) {
        if (acc[h][r] >= thr[h][r]) {
          int row = R0 + h * 16 + lq * 4 + r;
          int pos = atomicAdd(&cnt[row], 1);
          if (pos < CAP) cand[(size_t)row * CAP + pos] = (unsigned short)code;
        }
      }
  };

  loadB(0, b0);
  for (int t = 0; t < 128; t += 2) {
    loadB(t + 1, b1);
    p1step(b0, t);
    if (t + 2 < 128) loadB(t + 2, b0);
    p1step(b1, t + 1);
  }
}

// ---- exact f32 recheck + outputs: 4 rows/wave x 16 slot-lanes ----
__launch_bounds__(256)
__global__ void vq_recheck3(const float* __restrict__ z, const float* __restrict__ cb,
                            const float* __restrict__ ccg,
                            const int* __restrict__ cnt, const unsigned short* __restrict__ cand,
                            float* __restrict__ out, double* __restrict__ lacc) {
  __shared__ __align__(16) float zs[16][260];
  __shared__ double lpart[4];
  const int tid = threadIdx.x;
  const int w = tid >> 6, l = tid & 63;
  const int sl = l & 15;
  const int lr = w * 4 + (l >> 4);
  const size_t R0 = (size_t)blockIdx.x * 16;
  const size_t R = R0 + lr;

#pragma unroll
  for (int it = 0; it < 4; ++it) {
    int flat = it * 1024 + tid * 4;
    int r = flat >> 8, c = flat & 255;
    *(float4v*)&zs[r][c] = *(const float4v*)(z + R0 * DIM + flat);
  }
  __syncthreads();

  // zz: bitwise pairwise (verified)
  float zz;
  {
    const int b = (l >> 3) & 1, j = l & 7;
    const float* zr = zs[lr];
    float r = sqf(zr[b * 128 + j]);
    for (int i = 8; i < 128; i += 8) r = __fadd_rn(r, sqf(zr[b * 128 + i + j]));
    float rr[16];
    const int gbase = l & 48;
#pragma unroll
    for (int j2 = 0; j2 < 16; ++j2) rr[j2] = __shfl(r, gbase + j2, 64);
    float b0 = __fadd_rn(__fadd_rn(__fadd_rn(rr[0], rr[1]), __fadd_rn(rr[2], rr[3])),
                         __fadd_rn(__fadd_rn(rr[4], rr[5]), __fadd_rn(rr[6], rr[7])));
    float b1 = __fadd_rn(__fadd_rn(__fadd_rn(rr[8], rr[9]), __fadd_rn(rr[10], rr[11])),
                         __fadd_rn(__fadd_rn(rr[12], rr[13]), __fadd_rn(rr[14], rr[15])));
    zz = __fadd_rn(b0, b1);
  }

  // exact d (EXACT verified op order; cc from precomputed exact table)
  auto exact_d = [&](int code) -> float {
    const float* cr = cb + (size_t)code * DIM;
    float acc = 0.f;
    const float* zr = zs[lr];
    for (int k = 0; k < DIM; k += 4) {
      float4v zf = *(const float4v*)&zr[k];
      float4v cf = *(const float4v*)&cr[k];
      acc = fmaf(zf[0], cf[0], acc);
      acc = fmaf(zf[1], cf[1], acc);
      acc = fmaf(zf[2], cf[2], acc);
      acc = fmaf(zf[3], cf[3], acc);
    }
    return __fsub_rn(__fadd_rn(zz, ccg[code]), 2.0f * acc);
  };

  int nc = cnt[R];
  float d = INFINITY;
  int idx = 0x7fffffff;
  if (nc > CAP) {
    for (int c0 = sl; c0 < KCODES; c0 += 16) {
      float dd = exact_d(c0);
      if (dd < d) { d = dd; idx = c0; }
    }
  } else {
    for (int s = sl; s < nc; s += 16) {
      int ci = cand[R * CAP + s];
      float dd = exact_d(ci);
      if (dd < d || (dd == d && ci < idx)) { d = dd; idx = ci; }
    }
  }
#pragma unroll
  for (int off = 8; off >= 1; off >>= 1) {
    float od = __shfl_xor(d, off, 16);
    int oi = __shfl_xor(idx, off, 16);
    if (od < d || (od == d && oi < idx)) { d = od; idx = oi; }
  }
  if (sl == 0) out[(size_t)NZ + 1 + R] = (float)idx;

  double lsum = 0.0;
#pragma unroll
  for (int r = 0; r < 4; ++r) {
    int wi = __shfl(idx, r * 16, 64);
    size_t Rr = R0 + w * 4 + r;
    const float* cw = cb + (size_t)wi * DIM;
    float4v q = *(const float4v*)(cw + l * 4);
    float4v zv = *(const float4v*)&zs[w * 4 + r][l * 4];
    float4v o;
#pragma unroll
    for (int c = 0; c < 4; ++c) {
      float dq = __fsub_rn(q[c], zv[c]);
      o[c] = __fadd_rn(zv[c], dq);
      lsum += (double)__fmul_rn(dq, dq);
    }
    *(float4v*)(out + Rr * DIM + l * 4) = o;
  }

#pragma unroll
  for (int off = 32; off; off >>= 1) lsum += __shfl_xor(lsum, off, 64);
  if (l == 0) lpart[w] = lsum;
  __syncthreads();
  if (tid == 0) atomicAdd(lacc, lpart[0] + lpart[1] + lpart[2] + lpart[3]);
}

__global__ void vq_finalize(const double* __restrict__ lacc, float* __restrict__ out) {
  double m = *lacc / (double)((size_t)N_ROWS * DIM);
  float mf = (float)m;
  out[NZ] = __fadd_rn(mf, __fmul_rn(0.25f, mf));
}

extern "C" void kernel_launch(void* const* d_in, const int* in_sizes, int n_in,
                              void* d_out, int out_size, void* d_ws, size_t ws_size,
                              hipStream_t stream) {
  const float* z = (const float*)d_in[0];
  const float* cb = (const float*)d_in[1];
  float* out = (float*)d_out;

  char* ws = (char*)d_ws;
  double* lacc = (double*)ws;                               // @0
  int* cnt = (int*)(ws + 4096);                             // 128 KB
  float* cc = (float*)(ws + 4096 + 131072);                 // 32 KB
  unsigned short* cand = (unsigned short*)(ws + 262144);    // 4 MB
  short* chi = (short*)(ws + 262144 + 4194304);             // 4 MB

  hipMemsetAsync(d_ws, 0, 4096 + 131072, stream);
  hipLaunchKernelGGL(vq_conv, dim3(KCODES * DIM / 8 / 256), dim3(256), 0, stream, cb, chi);
  hipLaunchKernelGGL(vq_cc2, dim3(KCODES / 16), dim3(256), 0, stream, cb, cc);
  hipLaunchKernelGGL(vq_screen2, dim3(N_ROWS / 64), dim3(256), 0, stream, z, chi, cnt, cand);
  hipLaunchKernelGGL(vq_recheck3, dim3(N_ROWS / 16), dim3(256), 0, stream, z, cb, cc, cnt, cand, out, lacc);
  hipLaunchKernelGGL(vq_finalize, dim3(1), dim3(1), 0, stream, lacc, out);
}

// Round 6
// 1345.637 us; speedup vs baseline: 2.9534x; 2.9534x over previous
//
#include <hip/hip_runtime.h>
#include <math.h>

#define N_ROWS 32768
#define KCODES 8192
#define DIM 256
#define NZ (N_ROWS * DIM)
#define CAP 64
#define W_PRUNE 2e-4f

typedef __attribute__((ext_vector_type(8))) short short8v;
typedef __attribute__((ext_vector_type(4))) float float4v;

__device__ __forceinline__ float sqf(float x) { return __fmul_rn(x, x); }

__device__ __forceinline__ unsigned short f2bf(float f) {
  unsigned u = __float_as_uint(f);
  return (unsigned short)((u + 0x7fffu + ((u >> 16) & 1u)) >> 16);
}

// ---- codebook f32 -> bf16 convert ----
__global__ void vq_conv(const float* __restrict__ cb, short* __restrict__ chi) {
  int i = blockIdx.x * blockDim.x + threadIdx.x;
  const float* p = cb + (size_t)i * 8;
  float4v f0 = *(const float4v*)p;
  float4v f1 = *(const float4v*)(p + 4);
  short8v v;
  v[0] = (short)f2bf(f0[0]); v[1] = (short)f2bf(f0[1]);
  v[2] = (short)f2bf(f0[2]); v[3] = (short)f2bf(f0[3]);
  v[4] = (short)f2bf(f1[0]); v[5] = (short)f2bf(f1[1]);
  v[6] = (short)f2bf(f1[2]); v[7] = (short)f2bf(f1[3]);
  *(short8v*)(chi + (size_t)i * 8) = v;
}

// ---- exact ||c||^2, numpy-pairwise bitwise (verified pattern) ----
__global__ void vq_cc2(const float* __restrict__ cb, float* __restrict__ cc) {
  __shared__ __align__(16) float cs[16][260];
  const int tid = threadIdx.x;
  const int l = tid & 63;
  const int lr = (tid >> 6) * 4 + (l >> 4);
  const size_t C0 = (size_t)blockIdx.x * 16;

#pragma unroll
  for (int it = 0; it < 4; ++it) {
    int flat = it * 1024 + tid * 4;
    int r = flat >> 8, c = flat & 255;
    *(float4v*)&cs[r][c] = *(const float4v*)(cb + C0 * DIM + flat);
  }
  __syncthreads();

  const int b = (l >> 3) & 1, j = l & 7;
  const float* cr = cs[lr];
  float r = sqf(cr[b * 128 + j]);
  for (int i = 8; i < 128; i += 8) r = __fadd_rn(r, sqf(cr[b * 128 + i + j]));
  float rr[16];
  const int gbase = l & 48;
#pragma unroll
  for (int j2 = 0; j2 < 16; ++j2) rr[j2] = __shfl(r, gbase + j2, 64);
  float b0 = __fadd_rn(__fadd_rn(__fadd_rn(rr[0], rr[1]), __fadd_rn(rr[2], rr[3])),
                       __fadd_rn(__fadd_rn(rr[4], rr[5]), __fadd_rn(rr[6], rr[7])));
  float b1 = __fadd_rn(__fadd_rn(__fadd_rn(rr[8], rr[9]), __fadd_rn(rr[10], rr[11])),
                       __fadd_rn(__fadd_rn(rr[12], rr[13]), __fadd_rn(rr[14], rr[15])));
  if ((l & 15) == 0) cc[C0 + lr] = __fadd_rn(b0, b1);
}

// ---- screen v2 (unchanged from round 5; correct, fast) ----
__launch_bounds__(256, 2)
__global__ void vq_screen2(const float* __restrict__ z, const short* __restrict__ chi,
                           int* __restrict__ cnt, unsigned short* __restrict__ cand) {
  __shared__ __align__(16) float smax[64][4];
  const int tid = threadIdx.x;
  const int w = tid >> 6, l = tid & 63;
  const int lc = l & 15;
  const int lq = l >> 4;
  const int R0 = blockIdx.x * 64;

  short8v a[4][8];
#pragma unroll
  for (int h = 0; h < 4; ++h) {
    const float* zr = z + (size_t)(R0 + h * 16 + lc) * DIM + lq * 8;
#pragma unroll
    for (int s = 0; s < 8; ++s) {
      const float* p = zr + s * 32;
      float4v f0 = *(const float4v*)p;
      float4v f1 = *(const float4v*)(p + 4);
      short8v v;
      v[0] = (short)f2bf(f0[0]); v[1] = (short)f2bf(f0[1]);
      v[2] = (short)f2bf(f0[2]); v[3] = (short)f2bf(f0[3]);
      v[4] = (short)f2bf(f1[0]); v[5] = (short)f2bf(f1[1]);
      v[6] = (short)f2bf(f1[2]); v[7] = (short)f2bf(f1[3]);
      a[h][s] = v;
    }
  }

  short8v b0[8], b1[8];
  auto loadB = [&](int t, short8v (&br)[8]) {
    const short* cbase = chi + (size_t)(t * 64 + w * 16 + lc) * DIM + lq * 8;
#pragma unroll
    for (int s = 0; s < 8; ++s) br[s] = *(const short8v*)(cbase + s * 32);
  };
  auto mstep = [&](const short8v (&br)[8], float4v (&acc)[4]) {
#pragma unroll
    for (int s = 0; s < 8; ++s)
#pragma unroll
      for (int h = 0; h < 4; ++h)
        acc[h] = __builtin_amdgcn_mfma_f32_16x16x32_bf16(a[h][s], br[s], acc[h], 0, 0, 0);
  };

  float rmx[4][4];
#pragma unroll
  for (int h = 0; h < 4; ++h)
#pragma unroll
    for (int r = 0; r < 4; ++r) rmx[h][r] = -INFINITY;

  auto p0step = [&](const short8v (&br)[8]) {
    float4v acc[4] = {{0.f,0.f,0.f,0.f},{0.f,0.f,0.f,0.f},{0.f,0.f,0.f,0.f},{0.f,0.f,0.f,0.f}};
    mstep(br, acc);
#pragma unroll
    for (int h = 0; h < 4; ++h)
#pragma unroll
      for (int r = 0; r < 4; ++r) rmx[h][r] = fmaxf(rmx[h][r], acc[h][r]);
  };

  loadB(0, b0);
  for (int i = 0; i < 32; i += 2) {
    loadB(i * 4 + 4, b1);
    p0step(b0);
    if (i + 2 < 32) loadB(i * 4 + 8, b0);
    p0step(b1);
  }

#pragma unroll
  for (int h = 0; h < 4; ++h)
#pragma unroll
    for (int r = 0; r < 4; ++r) {
      float m = rmx[h][r];
      m = fmaxf(m, __shfl_xor(m, 1, 16));
      m = fmaxf(m, __shfl_xor(m, 2, 16));
      m = fmaxf(m, __shfl_xor(m, 4, 16));
      m = fmaxf(m, __shfl_xor(m, 8, 16));
      if (lc == 0) smax[h * 16 + lq * 4 + r][w] = m;
    }
  __syncthreads();
  float thr[4][4];
#pragma unroll
  for (int h = 0; h < 4; ++h)
#pragma unroll
    for (int r = 0; r < 4; ++r) {
      float4v mm = *(const float4v*)smax[h * 16 + lq * 4 + r];
      thr[h][r] = fmaxf(fmaxf(mm[0], mm[1]), fmaxf(mm[2], mm[3])) - W_PRUNE;
    }

  auto p1step = [&](const short8v (&br)[8], int t) {
    float4v acc[4] = {{0.f,0.f,0.f,0.f},{0.f,0.f,0.f,0.f},{0.f,0.f,0.f,0.f},{0.f,0.f,0.f,0.f}};
    mstep(br, acc);
    const int code = t * 64 + w * 16 + lc;
#pragma unroll
    for (int h = 0; h < 4; ++h)
#pragma unroll
      for (int r = 0; r < 4; ++r) {
        if (acc[h][r] >= thr[h][r]) {
          int row = R0 + h * 16 + lq * 4 + r;
          int pos = atomicAdd(&cnt[row], 1);
          if (pos < CAP) cand[(size_t)row * CAP + pos] = (unsigned short)code;
        }
      }
  };

  loadB(0, b0);
  for (int t = 0; t < 128; t += 2) {
    loadB(t + 1, b1);
    p1step(b0, t);
    if (t + 2 < 128) loadB(t + 2, b0);
    p1step(b1, t + 1);
  }
}

// ---- argmin over candidates ONLY (hot path, no fallback code) ----
__launch_bounds__(256)
__global__ void vq_argmin(const float* __restrict__ z, const float* __restrict__ cb,
                          const float* __restrict__ ccg, const int* __restrict__ cnt,
                          const unsigned short* __restrict__ cand, int* __restrict__ widx) {
  __shared__ __align__(16) float zs[16][260];
  const int tid = threadIdx.x;
  const int w = tid >> 6, l = tid & 63;
  const int sl = l & 15;
  const int lr = w * 4 + (l >> 4);
  const size_t R0 = (size_t)blockIdx.x * 16;
  const size_t R = R0 + lr;

#pragma unroll
  for (int it = 0; it < 4; ++it) {
    int flat = it * 1024 + tid * 4;
    int r = flat >> 8, c = flat & 255;
    *(float4v*)&zs[r][c] = *(const float4v*)(z + R0 * DIM + flat);
  }
  __syncthreads();

  // zz: bitwise pairwise (verified)
  float zz;
  {
    const int b = (l >> 3) & 1, j = l & 7;
    const float* zr = zs[lr];
    float r = sqf(zr[b * 128 + j]);
    for (int i = 8; i < 128; i += 8) r = __fadd_rn(r, sqf(zr[b * 128 + i + j]));
    float rr[16];
    const int gbase = l & 48;
#pragma unroll
    for (int j2 = 0; j2 < 16; ++j2) rr[j2] = __shfl(r, gbase + j2, 64);
    float b0 = __fadd_rn(__fadd_rn(__fadd_rn(rr[0], rr[1]), __fadd_rn(rr[2], rr[3])),
                         __fadd_rn(__fadd_rn(rr[4], rr[5]), __fadd_rn(rr[6], rr[7])));
    float b1 = __fadd_rn(__fadd_rn(__fadd_rn(rr[8], rr[9]), __fadd_rn(rr[10], rr[11])),
                         __fadd_rn(__fadd_rn(rr[12], rr[13]), __fadd_rn(rr[14], rr[15])));
    zz = __fadd_rn(b0, b1);
  }

  int nc = cnt[R];
  if (nc > CAP) nc = CAP;  // overflow rows fixed by vq_rescan
  float d = INFINITY;
  int idx = 0x7fffffff;
  for (int s = sl; s < nc; s += 16) {
    int ci = cand[R * CAP + s];
    const float* cr = cb + (size_t)ci * DIM;
    const float* zr = zs[lr];
    float acc = 0.f;
    for (int k = 0; k < DIM; k += 4) {
      float4v zf = *(const float4v*)&zr[k];
      float4v cf = *(const float4v*)&cr[k];
      acc = fmaf(zf[0], cf[0], acc);
      acc = fmaf(zf[1], cf[1], acc);
      acc = fmaf(zf[2], cf[2], acc);
      acc = fmaf(zf[3], cf[3], acc);
    }
    float dd = __fsub_rn(__fadd_rn(zz, ccg[ci]), 2.0f * acc);
    if (dd < d || (dd == d && ci < idx)) { d = dd; idx = ci; }
  }
#pragma unroll
  for (int off = 8; off >= 1; off >>= 1) {
    float od = __shfl_xor(d, off, 16);
    int oi = __shfl_xor(idx, off, 16);
    if (od < d || (od == d && oi < idx)) { d = od; idx = oi; }
  }
  if (sl == 0) widx[R] = (idx == 0x7fffffff) ? 0 : idx;
}

// ---- rescan: ONLY rows whose candidate list overflowed (cold; ~never runs) ----
__launch_bounds__(256)
__global__ void vq_rescan(const float* __restrict__ z, const float* __restrict__ cb,
                          const float* __restrict__ ccg, const int* __restrict__ cnt,
                          int* __restrict__ widx) {
  const int tid = threadIdx.x;
  const int w = tid >> 6, l = tid & 63;
  const int R0 = blockIdx.x * 64 + w * 16;
  int c16 = 0;
  if (l < 16) c16 = cnt[R0 + l];
  unsigned long long ov = __ballot(l < 16 && c16 > CAP);
  while (ov) {
    int bit = __ffsll(ov) - 1;
    ov &= ov - 1;
    int row = R0 + bit;
    const float* zr = z + (size_t)row * DIM;
    // exact zz (verified op order)
    float r = 0.f;
    if (l < 16) {
      int b = l >> 3, j = l & 7;
      r = sqf(zr[b * 128 + j]);
      for (int i = 8; i < 128; i += 8) r = __fadd_rn(r, sqf(zr[b * 128 + i + j]));
    }
    float rr[16];
#pragma unroll
    for (int j2 = 0; j2 < 16; ++j2) rr[j2] = __shfl(r, j2, 64);
    float b0 = __fadd_rn(__fadd_rn(__fadd_rn(rr[0], rr[1]), __fadd_rn(rr[2], rr[3])),
                         __fadd_rn(__fadd_rn(rr[4], rr[5]), __fadd_rn(rr[6], rr[7])));
    float b1 = __fadd_rn(__fadd_rn(__fadd_rn(rr[8], rr[9]), __fadd_rn(rr[10], rr[11])),
                         __fadd_rn(__fadd_rn(rr[12], rr[13]), __fadd_rn(rr[14], rr[15])));
    float zz = __fadd_rn(b0, b1);

    float d = INFINITY;
    int idx = 0x7fffffff;
    for (int c = l; c < KCODES; c += 64) {
      const float* cr = cb + (size_t)c * DIM;
      float acc = 0.f;
      for (int k = 0; k < DIM; k += 4) {
        float4v zf = *(const float4v*)&zr[k];
        float4v cf = *(const float4v*)&cr[k];
        acc = fmaf(zf[0], cf[0], acc);
        acc = fmaf(zf[1], cf[1], acc);
        acc = fmaf(zf[2], cf[2], acc);
        acc = fmaf(zf[3], cf[3], acc);
      }
      float dd = __fsub_rn(__fadd_rn(zz, ccg[c]), 2.0f * acc);
      if (dd < d) { d = dd; idx = c; }
    }
#pragma unroll
    for (int off = 32; off; off >>= 1) {
      float od = __shfl_xor(d, off, 64);
      int oi = __shfl_xor(idx, off, 64);
      if (od < d || (od == d && oi < idx)) { d = od; idx = oi; }
    }
    if (l == 0) widx[row] = idx;
  }
}

// ---- streaming epilogue: z_q, index floats, loss ----
__launch_bounds__(256)
__global__ void vq_output(const float* __restrict__ z, const float* __restrict__ cb,
                          const int* __restrict__ widx, float* __restrict__ out,
                          double* __restrict__ lacc) {
  __shared__ double lpart[4];
  const int tid = threadIdx.x;
  const int w = tid >> 6, l = tid & 63;
  const size_t R0 = (size_t)blockIdx.x * 16;
  double lsum = 0.0;
#pragma unroll
  for (int r = 0; r < 4; ++r) {
    size_t R = R0 + w * 4 + r;
    int wi = widx[R];
    if (l == 0) out[(size_t)NZ + 1 + R] = (float)wi;
    const float* cw = cb + (size_t)wi * DIM;
    const float* zr = z + R * DIM;
    float4v q = *(const float4v*)(cw + l * 4);
    float4v zv = *(const float4v*)(zr + l * 4);
    float4v o;
#pragma unroll
    for (int c = 0; c < 4; ++c) {
      float dq = __fsub_rn(q[c], zv[c]);
      o[c] = __fadd_rn(zv[c], dq);
      lsum += (double)__fmul_rn(dq, dq);
    }
    *(float4v*)(out + R * DIM + l * 4) = o;
  }
#pragma unroll
  for (int off = 32; off; off >>= 1) lsum += __shfl_xor(lsum, off, 64);
  if (l == 0) lpart[w] = lsum;
  __syncthreads();
  if (tid == 0) atomicAdd(lacc, lpart[0] + lpart[1] + lpart[2] + lpart[3]);
}

__global__ void vq_finalize(const double* __restrict__ lacc, float* __restrict__ out) {
  double m = *lacc / (double)((size_t)N_ROWS * DIM);
  float mf = (float)m;
  out[NZ] = __fadd_rn(mf, __fmul_rn(0.25f, mf));
}

extern "C" void kernel_launch(void* const* d_in, const int* in_sizes, int n_in,
                              void* d_out, int out_size, void* d_ws, size_t ws_size,
                              hipStream_t stream) {
  const float* z = (const float*)d_in[0];
  const float* cb = (const float*)d_in[1];
  float* out = (float*)d_out;

  char* ws = (char*)d_ws;
  double* lacc = (double*)ws;                            // @0, 4 KB region
  int* cnt = (int*)(ws + 4096);                          // 128 KB
  float* cc = (float*)(ws + 139264);                     // 32 KB
  int* widx = (int*)(ws + 172032);                       // 128 KB
  unsigned short* cand = (unsigned short*)(ws + 327680); // 4 MB
  short* chi = (short*)(ws + 327680 + 4194304);          // 4 MB

  hipMemsetAsync(d_ws, 0, 4096 + 131072, stream);
  hipLaunchKernelGGL(vq_conv, dim3(KCODES * DIM / 8 / 256), dim3(256), 0, stream, cb, chi);
  hipLaunchKernelGGL(vq_cc2, dim3(KCODES / 16), dim3(256), 0, stream, cb, cc);
  hipLaunchKernelGGL(vq_screen2, dim3(N_ROWS / 64), dim3(256), 0, stream, z, chi, cnt, cand);
  hipLaunchKernelGGL(vq_argmin, dim3(N_ROWS / 16), dim3(256), 0, stream, z, cb, cc, cnt, cand, widx);
  hipLaunchKernelGGL(vq_rescan, dim3(N_ROWS / 64), dim3(256), 0, stream, z, cb, cc, cnt, widx);
  hipLaunchKernelGGL(vq_output, dim3(N_ROWS / 16), dim3(256), 0, stream, z, cb, widx, out, lacc);
  hipLaunchKernelGGL(vq_finalize, dim3(1), dim3(1), 0, stream, lacc, out);
}

// Round 7
// 499.392 us; speedup vs baseline: 7.9580x; 2.6946x over previous
//
#include <hip/hip_runtime.h>
#include <math.h>

#define N_ROWS 32768
#define KCODES 8192
#define DIM 256
#define NZ (N_ROWS * DIM)
#define CAP 64
#define W_PRUNE 1.5e-4f

typedef __attribute__((ext_vector_type(8))) short short8v;
typedef __attribute__((ext_vector_type(4))) float float4v;

__device__ __forceinline__ float sqf(float x) { return __fmul_rn(x, x); }

__device__ __forceinline__ unsigned short f2bf(float f) {
  unsigned u = __float_as_uint(f);
  return (unsigned short)((u + 0x7fffu + ((u >> 16) & 1u)) >> 16);
}

// ---- codebook f32 -> bf16 convert (linear layout; stage pre-swizzles reads) ----
__global__ void vq_conv(const float* __restrict__ cb, short* __restrict__ chi) {
  int i = blockIdx.x * blockDim.x + threadIdx.x;
  const float* p = cb + (size_t)i * 8;
  float4v f0 = *(const float4v*)p;
  float4v f1 = *(const float4v*)(p + 4);
  short8v v;
  v[0] = (short)f2bf(f0[0]); v[1] = (short)f2bf(f0[1]);
  v[2] = (short)f2bf(f0[2]); v[3] = (short)f2bf(f0[3]);
  v[4] = (short)f2bf(f1[0]); v[5] = (short)f2bf(f1[1]);
  v[6] = (short)f2bf(f1[2]); v[7] = (short)f2bf(f1[3]);
  *(short8v*)(chi + (size_t)i * 8) = v;
}

// ---- exact ||c||^2, numpy-pairwise bitwise (verified pattern) ----
__global__ void vq_cc2(const float* __restrict__ cb, float* __restrict__ cc) {
  __shared__ __align__(16) float cs[16][260];
  const int tid = threadIdx.x;
  const int l = tid & 63;
  const int lr = (tid >> 6) * 4 + (l >> 4);
  const size_t C0 = (size_t)blockIdx.x * 16;

#pragma unroll
  for (int it = 0; it < 4; ++it) {
    int flat = it * 1024 + tid * 4;
    int r = flat >> 8, c = flat & 255;
    *(float4v*)&cs[r][c] = *(const float4v*)(cb + C0 * DIM + flat);
  }
  __syncthreads();

  const int b = (l >> 3) & 1, j = l & 7;
  const float* cr = cs[lr];
  float r = sqf(cr[b * 128 + j]);
  for (int i = 8; i < 128; i += 8) r = __fadd_rn(r, sqf(cr[b * 128 + i + j]));
  float rr[16];
  const int gbase = l & 48;
#pragma unroll
  for (int j2 = 0; j2 < 16; ++j2) rr[j2] = __shfl(r, gbase + j2, 64);
  float b0 = __fadd_rn(__fadd_rn(__fadd_rn(rr[0], rr[1]), __fadd_rn(rr[2], rr[3])),
                       __fadd_rn(__fadd_rn(rr[4], rr[5]), __fadd_rn(rr[6], rr[7])));
  float b1 = __fadd_rn(__fadd_rn(__fadd_rn(rr[8], rr[9]), __fadd_rn(rr[10], rr[11])),
                       __fadd_rn(__fadd_rn(rr[12], rr[13]), __fadd_rn(rr[14], rr[15])));
  if ((l & 15) == 0) cc[C0 + lr] = __fadd_rn(b0, b1);
}

// ---- screen v3: LDS-staged B (proven DMA+swizzle) + threshold-emit ----
// 512 blocks x 256 thr. Block = 64 rows. Wave w owns code-quarter w (16 codes
// of each 64-code tile) x all 64 rows (4 h-frags in registers).
// Pass 0: even tiles (half sample) -> per-row max. Pass 1: all tiles, emit.
__launch_bounds__(256, 2)
__global__ void vq_screen3(const float* __restrict__ z, const short* __restrict__ chi,
                           int* __restrict__ cnt, unsigned short* __restrict__ cand) {
  __shared__ __align__(16) short cs[2][64 * DIM];  // 2 x 32 KB
  __shared__ __align__(16) float smax[64][4];
  const int tid = threadIdx.x;
  const int w = tid >> 6, l = tid & 63;
  const int lc = l & 15;   // frag col lane (code within quarter)
  const int lq = l >> 4;   // k-quadrant / acc row group
  const int R0 = blockIdx.x * 64;

  // A-frags (validated pattern): row = R0 + h*16 + lc, k = s*32 + lq*8
  short8v a[4][8];
#pragma unroll
  for (int h = 0; h < 4; ++h) {
    const float* zr = z + (size_t)(R0 + h * 16 + lc) * DIM + lq * 8;
#pragma unroll
    for (int s = 0; s < 8; ++s) {
      const float* p = zr + s * 32;
      float4v f0 = *(const float4v*)p;
      float4v f1 = *(const float4v*)(p + 4);
      short8v v;
      v[0] = (short)f2bf(f0[0]); v[1] = (short)f2bf(f0[1]);
      v[2] = (short)f2bf(f0[2]); v[3] = (short)f2bf(f0[3]);
      v[4] = (short)f2bf(f1[0]); v[5] = (short)f2bf(f1[1]);
      v[6] = (short)f2bf(f1[2]); v[7] = (short)f2bf(f1[3]);
      a[h][s] = v;
    }
  }

  // stage: linear LDS dest (wave-uniform base; HW adds lane*16), XOR-preswizzled src
  auto stage = [&](int t, int bufi) {
    const char* tb = (const char*)chi + (size_t)t * (64 * DIM * 2);
#pragma unroll
    for (int p = 0; p < 8; ++p) {
      int i = p * 256 + w * 64 + l;
      int row = i >> 5, c = i & 31;
      const char* g = tb + (size_t)(((row << 5) + (c ^ (row & 7))) << 4);
      short* dst = (short*)cs[bufi] + (size_t)(p * 256 + w * 64) * 8;
      __builtin_amdgcn_global_load_lds(
          (const __attribute__((address_space(1))) unsigned int*)g,
          (__attribute__((address_space(3))) unsigned int*)dst, 16, 0, 0);
    }
  };
  // swizzled LDS read of this wave's code-quarter fragments
  auto ldsB = [&](int bufi, short8v (&br)[8]) {
    const int row = w * 16 + lc;
    const int sw = (row & 7) << 4;
    const char* rb = (const char*)cs[bufi] + ((size_t)row << 9);
#pragma unroll
    for (int s = 0; s < 8; ++s) {
      int koff = s * 64 + (lq << 4);
      br[s] = *(const short8v*)(rb + (koff ^ sw));
    }
  };
  auto mstep = [&](const short8v (&br)[8], float4v (&acc)[4]) {
#pragma unroll
    for (int s = 0; s < 8; ++s)
#pragma unroll
      for (int h = 0; h < 4; ++h)
        acc[h] = __builtin_amdgcn_mfma_f32_16x16x32_bf16(a[h][s], br[s], acc[h], 0, 0, 0);
  };

  // ---- pass 0: even tiles -> per-row sample max ----
  float rmx[4][4];
#pragma unroll
  for (int h = 0; h < 4; ++h)
#pragma unroll
    for (int r = 0; r < 4; ++r) rmx[h][r] = -INFINITY;

  stage(0, 0);
  __syncthreads();
  for (int i = 0; i < 64; ++i) {
    int cur = i & 1;
    if (i + 1 < 64) stage(2 * (i + 1), cur ^ 1);
    short8v b[8];
    ldsB(cur, b);
    float4v acc[4] = {{0.f,0.f,0.f,0.f},{0.f,0.f,0.f,0.f},{0.f,0.f,0.f,0.f},{0.f,0.f,0.f,0.f}};
    mstep(b, acc);
#pragma unroll
    for (int h = 0; h < 4; ++h)
#pragma unroll
      for (int r = 0; r < 4; ++r) rmx[h][r] = fmaxf(rmx[h][r], acc[h][r]);
    __syncthreads();
  }

  // cross-lane + cross-wave row max -> thresholds
#pragma unroll
  for (int h = 0; h < 4; ++h)
#pragma unroll
    for (int r = 0; r < 4; ++r) {
      float m = rmx[h][r];
      m = fmaxf(m, __shfl_xor(m, 1, 16));
      m = fmaxf(m, __shfl_xor(m, 2, 16));
      m = fmaxf(m, __shfl_xor(m, 4, 16));
      m = fmaxf(m, __shfl_xor(m, 8, 16));
      if (lc == 0) smax[h * 16 + lq * 4 + r][w] = m;
    }
  __syncthreads();
  float thr[4][4];
#pragma unroll
  for (int h = 0; h < 4; ++h)
#pragma unroll
    for (int r = 0; r < 4; ++r) {
      float4v mm = *(const float4v*)smax[h * 16 + lq * 4 + r];
      thr[h][r] = fmaxf(fmaxf(mm[0], mm[1]), fmaxf(mm[2], mm[3])) - W_PRUNE;
    }
  __syncthreads();

  // ---- pass 1: all tiles, emit scores >= thr ----
  stage(0, 0);
  __syncthreads();
  for (int t = 0; t < 128; ++t) {
    int cur = t & 1;
    if (t + 1 < 128) stage(t + 1, cur ^ 1);
    short8v b[8];
    ldsB(cur, b);
    float4v acc[4] = {{0.f,0.f,0.f,0.f},{0.f,0.f,0.f,0.f},{0.f,0.f,0.f,0.f},{0.f,0.f,0.f,0.f}};
    mstep(b, acc);
    const int code = t * 64 + w * 16 + lc;
#pragma unroll
    for (int h = 0; h < 4; ++h)
#pragma unroll
      for (int r = 0; r < 4; ++r) {
        if (acc[h][r] >= thr[h][r]) {
          int row = R0 + h * 16 + lq * 4 + r;
          int pos = atomicAdd(&cnt[row], 1);
          if (pos < CAP) cand[(size_t)row * CAP + pos] = (unsigned short)code;
        }
      }
    __syncthreads();
  }
}

// ---- argmin over candidates ONLY (hot path; unchanged, verified) ----
__launch_bounds__(256)
__global__ void vq_argmin(const float* __restrict__ z, const float* __restrict__ cb,
                          const float* __restrict__ ccg, const int* __restrict__ cnt,
                          const unsigned short* __restrict__ cand, int* __restrict__ widx) {
  __shared__ __align__(16) float zs[16][260];
  const int tid = threadIdx.x;
  const int w = tid >> 6, l = tid & 63;
  const int sl = l & 15;
  const int lr = w * 4 + (l >> 4);
  const size_t R0 = (size_t)blockIdx.x * 16;
  const size_t R = R0 + lr;

#pragma unroll
  for (int it = 0; it < 4; ++it) {
    int flat = it * 1024 + tid * 4;
    int r = flat >> 8, c = flat & 255;
    *(float4v*)&zs[r][c] = *(const float4v*)(z + R0 * DIM + flat);
  }
  __syncthreads();

  float zz;
  {
    const int b = (l >> 3) & 1, j = l & 7;
    const float* zr = zs[lr];
    float r = sqf(zr[b * 128 + j]);
    for (int i = 8; i < 128; i += 8) r = __fadd_rn(r, sqf(zr[b * 128 + i + j]));
    float rr[16];
    const int gbase = l & 48;
#pragma unroll
    for (int j2 = 0; j2 < 16; ++j2) rr[j2] = __shfl(r, gbase + j2, 64);
    float b0 = __fadd_rn(__fadd_rn(__fadd_rn(rr[0], rr[1]), __fadd_rn(rr[2], rr[3])),
                         __fadd_rn(__fadd_rn(rr[4], rr[5]), __fadd_rn(rr[6], rr[7])));
    float b1 = __fadd_rn(__fadd_rn(__fadd_rn(rr[8], rr[9]), __fadd_rn(rr[10], rr[11])),
                         __fadd_rn(__fadd_rn(rr[12], rr[13]), __fadd_rn(rr[14], rr[15])));
    zz = __fadd_rn(b0, b1);
  }

  int nc = cnt[R];
  if (nc > CAP) nc = CAP;  // overflow rows fixed by vq_rescan
  float d = INFINITY;
  int idx = 0x7fffffff;
  for (int s = sl; s < nc; s += 16) {
    int ci = cand[R * CAP + s];
    const float* cr = cb + (size_t)ci * DIM;
    const float* zr = zs[lr];
    float acc = 0.f;
    for (int k = 0; k < DIM; k += 4) {
      float4v zf = *(const float4v*)&zr[k];
      float4v cf = *(const float4v*)&cr[k];
      acc = fmaf(zf[0], cf[0], acc);
      acc = fmaf(zf[1], cf[1], acc);
      acc = fmaf(zf[2], cf[2], acc);
      acc = fmaf(zf[3], cf[3], acc);
    }
    float dd = __fsub_rn(__fadd_rn(zz, ccg[ci]), 2.0f * acc);
    if (dd < d || (dd == d && ci < idx)) { d = dd; idx = ci; }
  }
#pragma unroll
  for (int off = 8; off >= 1; off >>= 1) {
    float od = __shfl_xor(d, off, 16);
    int oi = __shfl_xor(idx, off, 16);
    if (od < d || (od == d && oi < idx)) { d = od; idx = oi; }
  }
  if (sl == 0) widx[R] = (idx == 0x7fffffff) ? 0 : idx;
}

// ---- rescan: ONLY overflowed rows (safety net; unchanged, verified) ----
__launch_bounds__(256)
__global__ void vq_rescan(const float* __restrict__ z, const float* __restrict__ cb,
                          const float* __restrict__ ccg, const int* __restrict__ cnt,
                          int* __restrict__ widx) {
  const int tid = threadIdx.x;
  const int w = tid >> 6, l = tid & 63;
  const int R0 = blockIdx.x * 64 + w * 16;
  int c16 = 0;
  if (l < 16) c16 = cnt[R0 + l];
  unsigned long long ov = __ballot(l < 16 && c16 > CAP);
  while (ov) {
    int bit = __ffsll(ov) - 1;
    ov &= ov - 1;
    int row = R0 + bit;
    const float* zr = z + (size_t)row * DIM;
    float r = 0.f;
    if (l < 16) {
      int b = l >> 3, j = l & 7;
      r = sqf(zr[b * 128 + j]);
      for (int i = 8; i < 128; i += 8) r = __fadd_rn(r, sqf(zr[b * 128 + i + j]));
    }
    float rr[16];
#pragma unroll
    for (int j2 = 0; j2 < 16; ++j2) rr[j2] = __shfl(r, j2, 64);
    float b0 = __fadd_rn(__fadd_rn(__fadd_rn(rr[0], rr[1]), __fadd_rn(rr[2], rr[3])),
                         __fadd_rn(__fadd_rn(rr[4], rr[5]), __fadd_rn(rr[6], rr[7])));
    float b1 = __fadd_rn(__fadd_rn(__fadd_rn(rr[8], rr[9]), __fadd_rn(rr[10], rr[11])),
                         __fadd_rn(__fadd_rn(rr[12], rr[13]), __fadd_rn(rr[14], rr[15])));
    float zz = __fadd_rn(b0, b1);

    float d = INFINITY;
    int idx = 0x7fffffff;
    for (int c = l; c < KCODES; c += 64) {
      const float* cr = cb + (size_t)c * DIM;
      float acc = 0.f;
      for (int k = 0; k < DIM; k += 4) {
        float4v zf = *(const float4v*)&zr[k];
        float4v cf = *(const float4v*)&cr[k];
        acc = fmaf(zf[0], cf[0], acc);
        acc = fmaf(zf[1], cf[1], acc);
        acc = fmaf(zf[2], cf[2], acc);
        acc = fmaf(zf[3], cf[3], acc);
      }
      float dd = __fsub_rn(__fadd_rn(zz, ccg[c]), 2.0f * acc);
      if (dd < d) { d = dd; idx = c; }
    }
#pragma unroll
    for (int off = 32; off; off >>= 1) {
      float od = __shfl_xor(d, off, 64);
      int oi = __shfl_xor(idx, off, 64);
      if (od < d || (od == d && oi < idx)) { d = od; idx = oi; }
    }
    if (l == 0) widx[row] = idx;
  }
}

// ---- streaming epilogue (unchanged, verified) ----
__launch_bounds__(256)
__global__ void vq_output(const float* __restrict__ z, const float* __restrict__ cb,
                          const int* __restrict__ widx, float* __restrict__ out,
                          double* __restrict__ lacc) {
  __shared__ double lpart[4];
  const int tid = threadIdx.x;
  const int w = tid >> 6, l = tid & 63;
  const size_t R0 = (size_t)blockIdx.x * 16;
  double lsum = 0.0;
#pragma unroll
  for (int r = 0; r < 4; ++r) {
    size_t R = R0 + w * 4 + r;
    int wi = widx[R];
    if (l == 0) out[(size_t)NZ + 1 + R] = (float)wi;
    const float* cw = cb + (size_t)wi * DIM;
    const float* zr = z + R * DIM;
    float4v q = *(const float4v*)(cw + l * 4);
    float4v zv = *(const float4v*)(zr + l * 4);
    float4v o;
#pragma unroll
    for (int c = 0; c < 4; ++c) {
      float dq = __fsub_rn(q[c], zv[c]);
      o[c] = __fadd_rn(zv[c], dq);
      lsum += (double)__fmul_rn(dq, dq);
    }
    *(float4v*)(out + R * DIM + l * 4) = o;
  }
#pragma unroll
  for (int off = 32; off; off >>= 1) lsum += __shfl_xor(lsum, off, 64);
  if (l == 0) lpart[w] = lsum;
  __syncthreads();
  if (tid == 0) atomicAdd(lacc, lpart[0] + lpart[1] + lpart[2] + lpart[3]);
}

__global__ void vq_finalize(const double* __restrict__ lacc, float* __restrict__ out) {
  double m = *lacc / (double)((size_t)N_ROWS * DIM);
  float mf = (float)m;
  out[NZ] = __fadd_rn(mf, __fmul_rn(0.25f, mf));
}

extern "C" void kernel_launch(void* const* d_in, const int* in_sizes, int n_in,
                              void* d_out, int out_size, void* d_ws, size_t ws_size,
                              hipStream_t stream) {
  const float* z = (const float*)d_in[0];
  const float* cb = (const float*)d_in[1];
  float* out = (float*)d_out;

  char* ws = (char*)d_ws;
  double* lacc = (double*)ws;                            // @0, 4 KB region
  int* cnt = (int*)(ws + 4096);                          // 128 KB
  float* cc = (float*)(ws + 139264);                     // 32 KB
  int* widx = (int*)(ws + 172032);                       // 128 KB
  unsigned short* cand = (unsigned short*)(ws + 327680); // 4 MB
  short* chi = (short*)(ws + 327680 + 4194304);          // 4 MB

  hipMemsetAsync(d_ws, 0, 4096 + 131072, stream);
  hipLaunchKernelGGL(vq_conv, dim3(KCODES * DIM / 8 / 256), dim3(256), 0, stream, cb, chi);
  hipLaunchKernelGGL(vq_cc2, dim3(KCODES / 16), dim3(256), 0, stream, cb, cc);
  hipLaunchKernelGGL(vq_screen3, dim3(N_ROWS / 64), dim3(256), 0, stream, z, chi, cnt, cand);
  hipLaunchKernelGGL(vq_argmin, dim3(N_ROWS / 16), dim3(256), 0, stream, z, cb, cc, cnt, cand, widx);
  hipLaunchKernelGGL(vq_rescan, dim3(N_ROWS / 64), dim3(256), 0, stream, z, cb, cc, cnt, widx);
  hipLaunchKernelGGL(vq_output, dim3(N_ROWS / 16), dim3(256), 0, stream, z, cb, widx, out, lacc);
  hipLaunchKernelGGL(vq_finalize, dim3(1), dim3(1), 0, stream, lacc, out);
}